// Round 1
// baseline (590.056 us; speedup 1.0000x reference)
//
#include <hip/hip_runtime.h>
#include <hip/hip_bf16.h>
#include <cstdint>
#include <cstddef>

// ---------------- types / helpers ----------------
typedef __bf16 bfx8 __attribute__((ext_vector_type(8)));   // 8 bf16 = 4 VGPR
typedef float  fx4  __attribute__((ext_vector_type(4)));   // MFMA C/D

#define MFMA_B16(a, b, c) __builtin_amdgcn_mfma_f32_16x16x32_bf16((a), (b), (c), 0, 0, 0)

#define GLD_LDS16(gsrc, ldst)                                                  \
  __builtin_amdgcn_global_load_lds(                                            \
      (const __attribute__((address_space(1))) void*)(gsrc),                   \
      (__attribute__((address_space(3))) void*)(ldst), 16, 0, 0)

static __device__ __forceinline__ unsigned short f2bf(float f) {
  union { float f; unsigned u; } v; v.f = f;
  unsigned r = v.u + 0x7fffu + ((v.u >> 16) & 1u);   // RTNE
  return (unsigned short)(r >> 16);
}

// problem constants
#define BB 4
#define TT 2048
#define DD 1024
#define HH 16
#define HD 64

// ---------------- cast x: f32 -> bf16 ----------------
__global__ void k_cast(const float* __restrict__ in, unsigned short* __restrict__ out, int n) {
  int i = (blockIdx.x * blockDim.x + threadIdx.x) * 4;
  int stride = gridDim.x * blockDim.x * 4;
  for (; i < n; i += stride) {
    float4 v = *(const float4*)(in + i);
    ushort4 o;
    o.x = f2bf(v.x); o.y = f2bf(v.y); o.z = f2bf(v.z); o.w = f2bf(v.w);
    *(ushort4*)(out + i) = o;
  }
}

// ---------------- transpose + cast: in[R][C] f32 -> out[C][R] bf16 ----------------
__global__ void k_transpose(const float* __restrict__ in, unsigned short* __restrict__ out,
                            int R, int C) {
  __shared__ float tile[32][33];
  int c0 = blockIdx.x * 32, r0 = blockIdx.y * 32;
  int tx = threadIdx.x, ty = threadIdx.y;   // 32 x 8
#pragma unroll
  for (int dy = 0; dy < 32; dy += 8)
    tile[ty + dy][tx] = in[(size_t)(r0 + ty + dy) * C + (c0 + tx)];
  __syncthreads();
#pragma unroll
  for (int dy = 0; dy < 32; dy += 8)
    out[(size_t)(c0 + ty + dy) * R + (r0 + tx)] = f2bf(tile[tx][ty + dy]);
}

// ---------------- GEMM: C[M][N] = A[M][K] * Bt[N][K]^T   (bf16 in, f32 acc) ----------------
// EPI==0: write f32 to out[M][N].  EPI==1: scatter bf16 to q[B,H,T,HD], k[B,H,T,HD], vT[B,H,HD,T].
template <int EPI>
__global__ __launch_bounds__(256) void k_gemm(
    const unsigned short* __restrict__ A,   // [M][K] bf16
    const unsigned short* __restrict__ Bt,  // [N][K] bf16
    float* __restrict__ outf,               // EPI==0
    int M, int N, int K,
    unsigned short* __restrict__ qb, unsigned short* __restrict__ kb,
    unsigned short* __restrict__ vtb) {
  constexpr int BM = 128, BN = 128, BK = 32;
  __shared__ __align__(16) unsigned short As[BM * BK];
  __shared__ __align__(16) unsigned short Bs[BN * BK];

  const int tid  = threadIdx.x;
  const int lane = tid & 63;
  const int w    = tid >> 6;       // wave 0..3
  const int wr   = w >> 1, wc = w & 1;
  const int n16  = lane & 15, g = lane >> 4;
  const int m0 = blockIdx.y * BM, n0 = blockIdx.x * BN;

  fx4 acc[4][4] = {};

  for (int k0 = 0; k0 < K; k0 += BK) {
    // stage A (8KB) + B (8KB): 2 issues each, 16B/lane, LDS dst = wave-uniform base + lane*16
#pragma unroll
    for (int iss = 0; iss < 2; ++iss) {
      int bo   = iss * 4096 + w * 1024 + lane * 16;  // byte offset in linear [128][32] bf16 tile
      int row  = bo >> 6;                            // 64 B per row
      int colb = bo & 63;
      const char* srcA = (const char*)A  + ((size_t)(m0 + row) * K + k0) * 2 + colb;
      const char* srcB = (const char*)Bt + ((size_t)(n0 + row) * K + k0) * 2 + colb;
      GLD_LDS16(srcA, (char*)As + iss * 4096 + w * 1024);
      GLD_LDS16(srcB, (char*)Bs + iss * 4096 + w * 1024);
    }
    __syncthreads();   // drains vmcnt(0) -> tiles resident

    bfx8 af[4], bf[4];
#pragma unroll
    for (int mi = 0; mi < 4; ++mi)
      af[mi] = *(const bfx8*)(const void*)&As[(wr * 64 + mi * 16 + n16) * BK + g * 8];
#pragma unroll
    for (int ni = 0; ni < 4; ++ni)
      bf[ni] = *(const bfx8*)(const void*)&Bs[(wc * 64 + ni * 16 + n16) * BK + g * 8];
#pragma unroll
    for (int mi = 0; mi < 4; ++mi)
#pragma unroll
      for (int ni = 0; ni < 4; ++ni)
        acc[mi][ni] = MFMA_B16(af[mi], bf[ni], acc[mi][ni]);
    __syncthreads();   // all waves done reading before next stage overwrites
  }

  // epilogue: C/D layout (verified): col = lane&15, row = (lane>>4)*4 + i
#pragma unroll
  for (int mi = 0; mi < 4; ++mi) {
#pragma unroll
    for (int ni = 0; ni < 4; ++ni) {
      int mrow = m0 + wr * 64 + mi * 16 + g * 4;
      int ncol = n0 + wc * 64 + ni * 16 + n16;
      if (EPI == 0) {
#pragma unroll
        for (int i = 0; i < 4; ++i)
          outf[(size_t)(mrow + i) * N + ncol] = acc[mi][ni][i];
      } else {
        int sec = ncol >> 10;         // 0=q 1=k 2=v
        int h   = (ncol >> 6) & 15;
        int d   = ncol & 63;
#pragma unroll
        for (int i = 0; i < 4; ++i) {
          int mm = mrow + i;
          int b  = mm >> 11;          // T = 2048
          int t  = mm & 2047;
          unsigned short val = f2bf(acc[mi][ni][i]);
          if (sec == 0)
            qb[(((size_t)(b * HH + h) * TT + t) << 6) + d] = val;
          else if (sec == 1)
            kb[(((size_t)(b * HH + h) * TT + t) << 6) + d] = val;
          else
            vtb[((size_t)(b * HH + h) * HD + d) * TT + t] = val;
        }
      }
    }
  }
}

// ---------------- flash attention (causal) ----------------
// grid: B*H*(T/64) blocks, 256 thr (4 waves). wave w owns 16 q-rows.
__global__ __launch_bounds__(256) void k_attn(
    const unsigned short* __restrict__ qb,   // [B,H,T,HD]
    const unsigned short* __restrict__ kb,   // [B,H,T,HD]
    const unsigned short* __restrict__ vtb,  // [B,H,HD,T]
    unsigned short* __restrict__ yb) {       // [B*T, D] bf16
  __shared__ __align__(16) unsigned short P_lds[4][16][32];

  const int tid  = threadIdx.x;
  const int lane = tid & 63;
  const int w    = tid >> 6;
  const int n16  = lane & 15, g = lane >> 4;

  int blk = blockIdx.x;
  int qt  = blk & 31;          // T/64 = 32
  int h   = (blk >> 5) & 15;
  int b   = blk >> 9;
  const int q0 = qt * 64 + w * 16;

  const unsigned short* qrow_base = qb + ((size_t)(b * HH + h) * TT + q0) * HD;
  const unsigned short* krow_base = kb + (size_t)(b * HH + h) * TT * HD;
  const unsigned short* vt_base   = vtb + (size_t)(b * HH + h) * HD * TT;

  // Q fragments: A-frag row = lane&15 (q-row), k = (lane>>4)*8 + j over head-dim chunks
  bfx8 qf0 = *(const bfx8*)(const void*)(qrow_base + n16 * HD + 0 + g * 8);
  bfx8 qf1 = *(const bfx8*)(const void*)(qrow_base + n16 * HD + 32 + g * 8);

  fx4   of[4] = {};
  float m_i[4] = {-INFINITY, -INFINITY, -INFINITY, -INFINITY};
  float l_i[4] = {0.f, 0.f, 0.f, 0.f};

  const float SC    = 0.03125f;               // 1/sqrt(D) = 1/32
  const float LOG2E = 1.4426950408889634f;
  const int   kv_end = q0 + 16;                // max kv needed (exclusive)

  for (int kv0 = 0; kv0 < kv_end; kv0 += 32) {
    // S = Q * K^T  (two 16-wide kv tiles)
    fx4 sf[2];
#pragma unroll
    for (int t = 0; t < 2; ++t) {
      const unsigned short* kr = krow_base + (size_t)(kv0 + t * 16 + n16) * HD;
      bfx8 kf0 = *(const bfx8*)(const void*)(kr + g * 8);
      bfx8 kf1 = *(const bfx8*)(const void*)(kr + 32 + g * 8);
      fx4 z = {};
      z     = MFMA_B16(qf0, kf0, z);
      sf[t] = MFMA_B16(qf1, kf1, z);
    }

    float p0v[4], p1v[4], alpha[4];
#pragma unroll
    for (int i = 0; i < 4; ++i) {
      int qrow = q0 + g * 4 + i;
      float s0 = (kv0 + n16      <= qrow) ? sf[0][i] * SC : -INFINITY;
      float s1 = (kv0 + 16 + n16 <= qrow) ? sf[1][i] * SC : -INFINITY;
      float mx = fmaxf(s0, s1);
#pragma unroll
      for (int off = 1; off < 16; off <<= 1)
        mx = fmaxf(mx, __shfl_xor(mx, off));
      float mnew = fmaxf(m_i[i], mx);
      alpha[i] = exp2f((m_i[i] - mnew) * LOG2E);    // -inf -> 0 on first tile
      float p0 = exp2f((s0 - mnew) * LOG2E);        // masked (-inf) -> 0
      float p1 = exp2f((s1 - mnew) * LOG2E);
      p0v[i] = p0; p1v[i] = p1;
      float sum = p0 + p1;
#pragma unroll
      for (int off = 1; off < 16; off <<= 1)
        sum += __shfl_xor(sum, off);
      l_i[i] = l_i[i] * alpha[i] + sum;
      m_i[i] = mnew;
    }
#pragma unroll
    for (int nn = 0; nn < 4; ++nn)
#pragma unroll
      for (int i = 0; i < 4; ++i)
        of[nn][i] *= alpha[i];

    // P (C/D layout) -> LDS -> A-fragment layout
#pragma unroll
    for (int i = 0; i < 4; ++i) {
      P_lds[w][g * 4 + i][n16]      = f2bf(p0v[i]);
      P_lds[w][g * 4 + i][16 + n16] = f2bf(p1v[i]);
    }
    asm volatile("s_waitcnt lgkmcnt(0)" ::: "memory");   // wave-local ds_write -> ds_read
    bfx8 pa = *(const bfx8*)(const void*)&P_lds[w][n16][g * 8];

    // O += P * V   (V^T rows are kv-contiguous -> 16B loads)
#pragma unroll
    for (int nn = 0; nn < 4; ++nn) {
      bfx8 vf = *(const bfx8*)(const void*)(vt_base + (size_t)(nn * 16 + n16) * TT + kv0 + g * 8);
      of[nn] = MFMA_B16(pa, vf, of[nn]);
    }
  }

  // write y[b*T + qrow][h*64 + d]
#pragma unroll
  for (int nn = 0; nn < 4; ++nn)
#pragma unroll
    for (int i = 0; i < 4; ++i) {
      int qrow = q0 + g * 4 + i;
      float v  = of[nn][i] / l_i[i];
      yb[(size_t)(b * TT + qrow) * DD + h * HD + nn * 16 + n16] = f2bf(v);
    }
}

// ---------------- launch ----------------
extern "C" void kernel_launch(void* const* d_in, const int* in_sizes, int n_in,
                              void* d_out, int out_size, void* d_ws, size_t ws_size,
                              hipStream_t stream) {
  const float* x      = (const float*)d_in[0];
  const float* w_qkv  = (const float*)d_in[1];
  const float* w_proj = (const float*)d_in[2];
  float* out = (float*)d_out;

  char* ws = (char*)d_ws;
  // layout (bytes): xb 16MB | wqkvT 6MB | wprojT 2MB | qb 16MB | kb 16MB | vtb 16MB ; yb reuses xb
  unsigned short* xb     = (unsigned short*)(ws);
  unsigned short* wqkvT  = (unsigned short*)(ws + (size_t)(16u << 20));
  unsigned short* wprojT = (unsigned short*)(ws + (size_t)(22u << 20));
  unsigned short* qb     = (unsigned short*)(ws + (size_t)(24u << 20));
  unsigned short* kb     = (unsigned short*)(ws + (size_t)(40u << 20));
  unsigned short* vtb    = (unsigned short*)(ws + (size_t)(56u << 20));
  unsigned short* yb     = xb;   // x dead after GEMM1

  k_cast<<<4096, 256, 0, stream>>>(x, xb, BB * TT * DD);

  dim3 tb(32, 8);
  k_transpose<<<dim3(3 * DD / 32, DD / 32), tb, 0, stream>>>(w_qkv, wqkvT, DD, 3 * DD);
  k_transpose<<<dim3(DD / 32, DD / 32), tb, 0, stream>>>(w_proj, wprojT, DD, DD);

  // QKV projection: [8192,1024] x [1024,3072]
  k_gemm<1><<<dim3(3 * DD / 128, BB * TT / 128), 256, 0, stream>>>(
      xb, wqkvT, nullptr, BB * TT, 3 * DD, DD, qb, kb, vtb);

  // causal flash attention
  k_attn<<<BB * HH * (TT / 64), 256, 0, stream>>>(qb, kb, vtb, yb);

  // output projection: [8192,1024] x [1024,1024] -> f32 d_out
  k_gemm<0><<<dim3(DD / 128, BB * TT / 128), 256, 0, stream>>>(
      yb, wprojT, out, BB * TT, DD, DD, nullptr, nullptr, nullptr);
}

// Round 2
// 389.840 us; speedup vs baseline: 1.5136x; 1.5136x over previous
//
#include <hip/hip_runtime.h>
#include <hip/hip_bf16.h>
#include <cstdint>
#include <cstddef>

// ---------------- types / helpers ----------------
typedef __bf16 bfx8 __attribute__((ext_vector_type(8)));   // 8 bf16 = 4 VGPR
typedef float  fx4  __attribute__((ext_vector_type(4)));   // 16x16 MFMA C/D
typedef float  fx16 __attribute__((ext_vector_type(16)));  // 32x32 MFMA C/D

#define MFMA_B16(a, b, c)  __builtin_amdgcn_mfma_f32_16x16x32_bf16((a), (b), (c), 0, 0, 0)
#define MFMA32(a, b, c)    __builtin_amdgcn_mfma_f32_32x32x16_bf16((a), (b), (c), 0, 0, 0)

#define GLD_LDS16(gsrc, ldst)                                                  \
  __builtin_amdgcn_global_load_lds(                                            \
      (const __attribute__((address_space(1))) void*)(gsrc),                   \
      (__attribute__((address_space(3))) void*)(ldst), 16, 0, 0)

static __device__ __forceinline__ unsigned short f2bf(float f) {
  union { float f; unsigned u; } v; v.f = f;
  unsigned r = v.u + 0x7fffu + ((v.u >> 16) & 1u);   // RTNE
  return (unsigned short)(r >> 16);
}

static __device__ __forceinline__ bfx8 ldb8(const unsigned short* p) {
  return *(const bfx8*)(const void*)p;
}

static __device__ __forceinline__ unsigned pk2(float lo, float hi) {
  __hip_bfloat162 h2 = __float22bfloat162_rn(make_float2(lo, hi));
  union { __hip_bfloat162 h; unsigned u; } c; c.h = h2; return c.u;
}

// problem constants
#define BB 4
#define TT 2048
#define DD 1024
#define HH 16
#define HD 64

// ---------------- cast x: f32 -> bf16 ----------------
__global__ void k_cast(const float* __restrict__ in, unsigned short* __restrict__ out, int n) {
  int i = (blockIdx.x * blockDim.x + threadIdx.x) * 4;
  int stride = gridDim.x * blockDim.x * 4;
  for (; i < n; i += stride) {
    float4 v = *(const float4*)(in + i);
    ushort4 o;
    o.x = f2bf(v.x); o.y = f2bf(v.y); o.z = f2bf(v.z); o.w = f2bf(v.w);
    *(ushort4*)(out + i) = o;
  }
}

// ---------------- transpose + cast: in[R][C] f32 -> out[C][R] bf16 ----------------
__global__ void k_transpose(const float* __restrict__ in, unsigned short* __restrict__ out,
                            int R, int C) {
  __shared__ float tile[32][33];
  int c0 = blockIdx.x * 32, r0 = blockIdx.y * 32;
  int tx = threadIdx.x, ty = threadIdx.y;   // 32 x 8
#pragma unroll
  for (int dy = 0; dy < 32; dy += 8)
    tile[ty + dy][tx] = in[(size_t)(r0 + ty + dy) * C + (c0 + tx)];
  __syncthreads();
#pragma unroll
  for (int dy = 0; dy < 32; dy += 8)
    out[(size_t)(c0 + ty + dy) * R + (r0 + tx)] = f2bf(tile[tx][ty + dy]);
}

// ---------------- GEMM: C[M][N] = A[M][K] * Bt[N][K]^T   (bf16 in, f32 acc) ----------------
template <int EPI>
__global__ __launch_bounds__(256) void k_gemm(
    const unsigned short* __restrict__ A,   // [M][K] bf16
    const unsigned short* __restrict__ Bt,  // [N][K] bf16
    float* __restrict__ outf,               // EPI==0
    int M, int N, int K,
    unsigned short* __restrict__ qb, unsigned short* __restrict__ kb,
    unsigned short* __restrict__ vtb) {
  constexpr int BM = 128, BN = 128, BK = 32;
  __shared__ __align__(16) unsigned short As[BM * BK];
  __shared__ __align__(16) unsigned short Bs[BN * BK];

  const int tid  = threadIdx.x;
  const int lane = tid & 63;
  const int w    = tid >> 6;       // wave 0..3
  const int wr   = w >> 1, wc = w & 1;
  const int n16  = lane & 15, g = lane >> 4;
  const int m0 = blockIdx.y * BM, n0 = blockIdx.x * BN;

  fx4 acc[4][4] = {};

  for (int k0 = 0; k0 < K; k0 += BK) {
#pragma unroll
    for (int iss = 0; iss < 2; ++iss) {
      int bo   = iss * 4096 + w * 1024 + lane * 16;
      int row  = bo >> 6;
      int colb = bo & 63;
      const char* srcA = (const char*)A  + ((size_t)(m0 + row) * K + k0) * 2 + colb;
      const char* srcB = (const char*)Bt + ((size_t)(n0 + row) * K + k0) * 2 + colb;
      GLD_LDS16(srcA, (char*)As + iss * 4096 + w * 1024);
      GLD_LDS16(srcB, (char*)Bs + iss * 4096 + w * 1024);
    }
    __syncthreads();

    bfx8 af[4], bf[4];
#pragma unroll
    for (int mi = 0; mi < 4; ++mi)
      af[mi] = *(const bfx8*)(const void*)&As[(wr * 64 + mi * 16 + n16) * BK + g * 8];
#pragma unroll
    for (int ni = 0; ni < 4; ++ni)
      bf[ni] = *(const bfx8*)(const void*)&Bs[(wc * 64 + ni * 16 + n16) * BK + g * 8];
#pragma unroll
    for (int mi = 0; mi < 4; ++mi)
#pragma unroll
      for (int ni = 0; ni < 4; ++ni)
        acc[mi][ni] = MFMA_B16(af[mi], bf[ni], acc[mi][ni]);
    __syncthreads();
  }

  // epilogue: C/D layout: col = lane&15, row = (lane>>4)*4 + i
#pragma unroll
  for (int mi = 0; mi < 4; ++mi) {
#pragma unroll
    for (int ni = 0; ni < 4; ++ni) {
      int mrow = m0 + wr * 64 + mi * 16 + g * 4;
      int ncol = n0 + wc * 64 + ni * 16 + n16;
      if (EPI == 0) {
#pragma unroll
        for (int i = 0; i < 4; ++i)
          outf[(size_t)(mrow + i) * N + ncol] = acc[mi][ni][i];
      } else {
        int sec = ncol >> 10;         // 0=q 1=k 2=v
        int h   = (ncol >> 6) & 15;
        int d   = ncol & 63;
#pragma unroll
        for (int i = 0; i < 4; ++i) {
          int mm = mrow + i;
          int b  = mm >> 11;
          int t  = mm & 2047;
          unsigned short val = f2bf(acc[mi][ni][i]);
          if (sec == 0)
            qb[(((size_t)(b * HH + h) * TT + t) << 6) + d] = val;
          else if (sec == 1)
            kb[(((size_t)(b * HH + h) * TT + t) << 6) + d] = val;
          else
            vtb[((size_t)(b * HH + h) * HD + d) * TT + t] = val;
        }
      }
    }
  }
}

// ---------------- flash attention: swapped QK^T, lane-local softmax ----------------
// S^T = mfma32(K, Q): lane owns q = lane&31; regs hold kv = (r&3)+8*(r>>2)+4*hi.
// PV:  O^T = mfma32(V^T, P^T): lane owns q = lane&31; rows d.
template <bool MASK>
static __device__ __forceinline__ void attn_tile(
    const unsigned short* __restrict__ kr, const unsigned short* __restrict__ vr,
    const bfx8* qf, int lim, int hi,
    float& m, float& l, fx16& o0, fx16& o1) {

  bfx8 kf0 = ldb8(kr +  0), kf1 = ldb8(kr + 16), kf2 = ldb8(kr + 32), kf3 = ldb8(kr + 48);
  bfx8 vf00 = ldb8(vr), vf01 = ldb8(vr + 16);
  bfx8 vf10 = ldb8(vr + 32 * TT), vf11 = ldb8(vr + 32 * TT + 16);

  fx16 s = {};
  s = MFMA32(kf0, qf[0], s);
  s = MFMA32(kf1, qf[1], s);
  s = MFMA32(kf2, qf[2], s);
  s = MFMA32(kf3, qf[3], s);

  const float CL = 0.0450842346f;  // log2(e) / sqrt(D) = log2(e)/32
  float t[16];
#pragma unroll
  for (int r = 0; r < 16; ++r) {
    int koff = (r & 3) + 8 * (r >> 2);
    float v = s[r] * CL;
    t[r] = (!MASK || koff <= lim) ? v : -__builtin_inff();
  }
  float mx = fmaxf(t[0], t[1]);
#pragma unroll
  for (int r = 2; r < 16; ++r) mx = fmaxf(mx, t[r]);
  mx = fmaxf(mx, __shfl_xor(mx, 32));
  float mnew = fmaxf(m, mx);
  float alpha = exp2f(m - mnew);
  m = mnew;

  float p[16];
  float sum = 0.f;
#pragma unroll
  for (int r = 0; r < 16; ++r) { p[r] = exp2f(t[r] - mnew); sum += p[r]; }
  sum += __shfl_xor(sum, 32);
  l = l * alpha + sum;
#pragma unroll
  for (int r = 0; r < 16; ++r) { o0[r] *= alpha; o1[r] *= alpha; }

  // P (S^T C/D regs) -> PV B-fragment (slot (hi,j) <-> kv = 16c + 8*hi + j)
  union { unsigned u[4]; bfx8 v; } P0, P1;
#pragma unroll
  for (int c = 0; c < 2; ++c) {
    unsigned a0 = pk2(p[8*c+0], p[8*c+1]);
    unsigned a1 = pk2(p[8*c+2], p[8*c+3]);
    unsigned b0 = pk2(p[8*c+4], p[8*c+5]);
    unsigned b1 = pk2(p[8*c+6], p[8*c+7]);
    unsigned xa0 = __shfl_xor(a0, 32), xa1 = __shfl_xor(a1, 32);
    unsigned xb0 = __shfl_xor(b0, 32), xb1 = __shfl_xor(b1, 32);
    unsigned* U = c ? P1.u : P0.u;
    U[0] = hi ? xb0 : a0;   // k = 8*hi + 0,1
    U[1] = hi ? xb1 : a1;   // k = 8*hi + 2,3
    U[2] = hi ? b0 : xa0;   // k = 8*hi + 4,5
    U[3] = hi ? b1 : xa1;   // k = 8*hi + 6,7
  }
  o0 = MFMA32(vf00, P0.v, o0);
  o0 = MFMA32(vf01, P1.v, o0);
  o1 = MFMA32(vf10, P0.v, o1);
  o1 = MFMA32(vf11, P1.v, o1);
}

// grid: B*H*(T/128) blocks, 256 thr (4 waves). wave w owns 32 q-rows; no LDS.
__global__ __launch_bounds__(256) void k_attn(
    const unsigned short* __restrict__ qb,   // [B,H,T,HD]
    const unsigned short* __restrict__ kb,   // [B,H,T,HD]
    const unsigned short* __restrict__ vtb,  // [B,H,HD,T]
    unsigned short* __restrict__ yb) {       // [B*T, D] bf16
  const int tid  = threadIdx.x;
  const int lane = tid & 63;
  const int w    = tid >> 6;
  const int l31  = lane & 31;
  const int hi   = lane >> 5;

  int blk = blockIdx.x;
  int qt  = blk & 15;           // T/128 = 16
  int h   = (blk >> 4) & 15;
  int b   = blk >> 8;
  const int q0 = qt * 128 + w * 32;
  const size_t bh = (size_t)b * HH + h;

  // Q as B-fragment: col = q = lane&31, slot k = dc*16 + hi*8 + j
  const unsigned short* qp = qb + (bh * TT + q0 + l31) * HD + hi * 8;
  bfx8 qf[4];
#pragma unroll
  for (int dc = 0; dc < 4; ++dc) qf[dc] = ldb8(qp + dc * 16);

  const unsigned short* kr = kb + bh * TT * HD + (size_t)l31 * HD + hi * 8;
  const unsigned short* vr = vtb + (bh * HD + l31) * TT + hi * 8;

  fx16 o0 = {}, o1 = {};
  float m = -__builtin_inff(), l = 0.f;

  for (int kv0 = 0; kv0 < q0; kv0 += 32) {
    attn_tile<false>(kr, vr, qf, 0, hi, m, l, o0, o1);
    kr += 32 * HD;
    vr += 32;
  }
  attn_tile<true>(kr, vr, qf, l31 - 4 * hi, hi, m, l, o0, o1);

  float inv = 1.0f / l;
  // O^T: lane q = l31; d = dt*32 + (r&3) + 8*(r>>2) + 4*hi
  size_t ybase = (size_t)(b * TT + q0 + l31) * DD + h * HD + 4 * hi;
#pragma unroll
  for (int g = 0; g < 4; ++g) {
    ushort4 s4;
    s4.x = f2bf(o0[4*g+0] * inv); s4.y = f2bf(o0[4*g+1] * inv);
    s4.z = f2bf(o0[4*g+2] * inv); s4.w = f2bf(o0[4*g+3] * inv);
    *(ushort4*)(yb + ybase + 8 * g) = s4;
    s4.x = f2bf(o1[4*g+0] * inv); s4.y = f2bf(o1[4*g+1] * inv);
    s4.z = f2bf(o1[4*g+2] * inv); s4.w = f2bf(o1[4*g+3] * inv);
    *(ushort4*)(yb + ybase + 32 + 8 * g) = s4;
  }
}

// ---------------- launch ----------------
extern "C" void kernel_launch(void* const* d_in, const int* in_sizes, int n_in,
                              void* d_out, int out_size, void* d_ws, size_t ws_size,
                              hipStream_t stream) {
  const float* x      = (const float*)d_in[0];
  const float* w_qkv  = (const float*)d_in[1];
  const float* w_proj = (const float*)d_in[2];
  float* out = (float*)d_out;

  char* ws = (char*)d_ws;
  unsigned short* xb     = (unsigned short*)(ws);
  unsigned short* wqkvT  = (unsigned short*)(ws + (size_t)(16u << 20));
  unsigned short* wprojT = (unsigned short*)(ws + (size_t)(22u << 20));
  unsigned short* qb     = (unsigned short*)(ws + (size_t)(24u << 20));
  unsigned short* kb     = (unsigned short*)(ws + (size_t)(40u << 20));
  unsigned short* vtb    = (unsigned short*)(ws + (size_t)(56u << 20));
  unsigned short* yb     = xb;   // x dead after GEMM1

  k_cast<<<4096, 256, 0, stream>>>(x, xb, BB * TT * DD);

  dim3 tb(32, 8);
  k_transpose<<<dim3(3 * DD / 32, DD / 32), tb, 0, stream>>>(w_qkv, wqkvT, DD, 3 * DD);
  k_transpose<<<dim3(DD / 32, DD / 32), tb, 0, stream>>>(w_proj, wprojT, DD, DD);

  // QKV projection: [8192,1024] x [1024,3072]
  k_gemm<1><<<dim3(3 * DD / 128, BB * TT / 128), 256, 0, stream>>>(
      xb, wqkvT, nullptr, BB * TT, 3 * DD, DD, qb, kb, vtb);

  // causal flash attention
  k_attn<<<BB * HH * (TT / 128), 256, 0, stream>>>(qb, kb, vtb, yb);

  // output projection: [8192,1024] x [1024,1024] -> f32 d_out
  k_gemm<0><<<dim3(DD / 128, BB * TT / 128), 256, 0, stream>>>(
      yb, wprojT, out, BB * TT, DD, DD, nullptr, nullptr, nullptr);
}

// Round 3
// 261.535 us; speedup vs baseline: 2.2561x; 1.4906x over previous
//
#include <hip/hip_runtime.h>
#include <hip/hip_bf16.h>
#include <cstdint>
#include <cstddef>

// ---------------- types / helpers ----------------
typedef __bf16 bfx8 __attribute__((ext_vector_type(8)));   // 8 bf16 = 4 VGPR
typedef float  fx4  __attribute__((ext_vector_type(4)));   // 16x16 MFMA C/D
typedef float  fx16 __attribute__((ext_vector_type(16)));  // 32x32 MFMA C/D

#define MFMA_B16(a, b, c)  __builtin_amdgcn_mfma_f32_16x16x32_bf16((a), (b), (c), 0, 0, 0)
#define MFMA32(a, b, c)    __builtin_amdgcn_mfma_f32_32x32x16_bf16((a), (b), (c), 0, 0, 0)

#define GLD_LDS16(gsrc, ldst)                                                  \
  __builtin_amdgcn_global_load_lds(                                            \
      (const __attribute__((address_space(1))) void*)(gsrc),                   \
      (__attribute__((address_space(3))) void*)(ldst), 16, 0, 0)

static __device__ __forceinline__ unsigned short f2bf(float f) {
  union { float f; unsigned u; } v; v.f = f;
  unsigned r = v.u + 0x7fffu + ((v.u >> 16) & 1u);   // RTNE
  return (unsigned short)(r >> 16);
}

static __device__ __forceinline__ bfx8 ldb8(const unsigned short* p) {
  return *(const bfx8*)(const void*)p;
}

static __device__ __forceinline__ unsigned pk2(float lo, float hi) {
  __hip_bfloat162 h2 = __float22bfloat162_rn(make_float2(lo, hi));
  union { __hip_bfloat162 h; unsigned u; } c; c.h = h2; return c.u;
}

// scale 8 packed bf16 by s (unpack -> mul -> repack)
static __device__ __forceinline__ bfx8 scale8(bfx8 x, float s) {
  union { bfx8 v; unsigned u[4]; } a; a.v = x;
  union { bfx8 v; unsigned u[4]; } r;
#pragma unroll
  for (int j = 0; j < 4; ++j) {
    union { unsigned u; float f; } lo, hi;
    lo.u = a.u[j] << 16;
    hi.u = a.u[j] & 0xffff0000u;
    r.u[j] = pk2(lo.f * s, hi.f * s);
  }
  return r.v;
}

// problem constants
#define BB 4
#define TT 2048
#define DD 1024
#define HH 16
#define HD 64

// ---------------- cast x: f32 -> bf16 ----------------
__global__ void k_cast(const float* __restrict__ in, unsigned short* __restrict__ out, int n) {
  int i = (blockIdx.x * blockDim.x + threadIdx.x) * 4;
  int stride = gridDim.x * blockDim.x * 4;
  for (; i < n; i += stride) {
    float4 v = *(const float4*)(in + i);
    ushort4 o;
    o.x = f2bf(v.x); o.y = f2bf(v.y); o.z = f2bf(v.z); o.w = f2bf(v.w);
    *(ushort4*)(out + i) = o;
  }
}

// ---------------- transpose + cast: in[R][C] f32 -> out[C][R] bf16 ----------------
__global__ void k_transpose(const float* __restrict__ in, unsigned short* __restrict__ out,
                            int R, int C) {
  __shared__ float tile[32][33];
  int c0 = blockIdx.x * 32, r0 = blockIdx.y * 32;
  int tx = threadIdx.x, ty = threadIdx.y;   // 32 x 8
#pragma unroll
  for (int dy = 0; dy < 32; dy += 8)
    tile[ty + dy][tx] = in[(size_t)(r0 + ty + dy) * C + (c0 + tx)];
  __syncthreads();
#pragma unroll
  for (int dy = 0; dy < 32; dy += 8)
    out[(size_t)(c0 + ty + dy) * R + (r0 + tx)] = f2bf(tile[tx][ty + dy]);
}

// ---------------- GEMM: C[M][N] = A[M][K] * Bt[N][K]^T   (bf16 in, f32 acc) ----------------
template <int EPI>
__global__ __launch_bounds__(256) void k_gemm(
    const unsigned short* __restrict__ A,   // [M][K] bf16
    const unsigned short* __restrict__ Bt,  // [N][K] bf16
    float* __restrict__ outf,               // EPI==0
    int M, int N, int K,
    unsigned short* __restrict__ qb, unsigned short* __restrict__ kb,
    unsigned short* __restrict__ vtb) {
  constexpr int BM = 128, BN = 128, BK = 32;
  __shared__ __align__(16) unsigned short As[BM * BK];
  __shared__ __align__(16) unsigned short Bs[BN * BK];

  const int tid  = threadIdx.x;
  const int lane = tid & 63;
  const int w    = tid >> 6;       // wave 0..3
  const int wr   = w >> 1, wc = w & 1;
  const int n16  = lane & 15, g = lane >> 4;
  const int m0 = blockIdx.y * BM, n0 = blockIdx.x * BN;

  fx4 acc[4][4] = {};

  for (int k0 = 0; k0 < K; k0 += BK) {
#pragma unroll
    for (int iss = 0; iss < 2; ++iss) {
      int bo   = iss * 4096 + w * 1024 + lane * 16;
      int row  = bo >> 6;
      int colb = bo & 63;
      const char* srcA = (const char*)A  + ((size_t)(m0 + row) * K + k0) * 2 + colb;
      const char* srcB = (const char*)Bt + ((size_t)(n0 + row) * K + k0) * 2 + colb;
      GLD_LDS16(srcA, (char*)As + iss * 4096 + w * 1024);
      GLD_LDS16(srcB, (char*)Bs + iss * 4096 + w * 1024);
    }
    __syncthreads();

    bfx8 af[4], bf[4];
#pragma unroll
    for (int mi = 0; mi < 4; ++mi)
      af[mi] = *(const bfx8*)(const void*)&As[(wr * 64 + mi * 16 + n16) * BK + g * 8];
#pragma unroll
    for (int ni = 0; ni < 4; ++ni)
      bf[ni] = *(const bfx8*)(const void*)&Bs[(wc * 64 + ni * 16 + n16) * BK + g * 8];
#pragma unroll
    for (int mi = 0; mi < 4; ++mi)
#pragma unroll
      for (int ni = 0; ni < 4; ++ni)
        acc[mi][ni] = MFMA_B16(af[mi], bf[ni], acc[mi][ni]);
    __syncthreads();
  }

  // epilogue: C/D layout: col = lane&15, row = (lane>>4)*4 + i
#pragma unroll
  for (int mi = 0; mi < 4; ++mi) {
#pragma unroll
    for (int ni = 0; ni < 4; ++ni) {
      int mrow = m0 + wr * 64 + mi * 16 + g * 4;
      int ncol = n0 + wc * 64 + ni * 16 + n16;
      if (EPI == 0) {
#pragma unroll
        for (int i = 0; i < 4; ++i)
          outf[(size_t)(mrow + i) * N + ncol] = acc[mi][ni][i];
      } else {
        int sec = ncol >> 10;         // 0=q 1=k 2=v
        int h   = (ncol >> 6) & 15;
        int d   = ncol & 63;
#pragma unroll
        for (int i = 0; i < 4; ++i) {
          int mm = mrow + i;
          int b  = mm >> 11;
          int t  = mm & 2047;
          unsigned short val = f2bf(acc[mi][ni][i]);
          if (sec == 0)
            qb[(((size_t)(b * HH + h) * TT + t) << 6) + d] = val;
          else if (sec == 1)
            kb[(((size_t)(b * HH + h) * TT + t) << 6) + d] = val;
          else
            vtb[((size_t)(b * HH + h) * HD + d) * TT + t] = val;
        }
      }
    }
  }
}

// ---------------- flash attention ----------------
// Swapped QK^T: S^T = mfma32(K, Q); lane owns q-col = lane&31, regs hold 16 kv slots.
// log2e/sqrt(D) folded into Q, so S is already in log2 domain.
struct KVfrag { bfx8 k0, k1, k2, k3, v0, v1, v2, v3; };

static __device__ __forceinline__ void load_kv(
    KVfrag& f, const unsigned short* __restrict__ kbase,
    const unsigned short* __restrict__ vbase, int kv0) {
  const unsigned short* kr = kbase + (size_t)kv0 * HD;
  f.k0 = ldb8(kr);       f.k1 = ldb8(kr + 16);
  f.k2 = ldb8(kr + 32);  f.k3 = ldb8(kr + 48);
  const unsigned short* vr = vbase + kv0;
  f.v0 = ldb8(vr);            f.v1 = ldb8(vr + 16);
  f.v2 = ldb8(vr + 32 * TT);  f.v3 = ldb8(vr + 32 * TT + 16);
}

template <bool MASK>
static __device__ __forceinline__ void attn_tile(
    const KVfrag& f, const bfx8* qf, int lim, int hi,
    float& m, float& l, fx16& o0, fx16& o1) {
  fx16 s = {};
  s = MFMA32(f.k0, qf[0], s);
  s = MFMA32(f.k1, qf[1], s);
  s = MFMA32(f.k2, qf[2], s);
  s = MFMA32(f.k3, qf[3], s);

  float t[16];
#pragma unroll
  for (int r = 0; r < 16; ++r) {
    int koff = (r & 3) + 8 * (r >> 2);
    t[r] = (!MASK || koff <= lim) ? s[r] : -__builtin_inff();
  }
  // local max (tree, 15 ops depth 4)
  float x0 = fmaxf(t[0], t[1]),   x1 = fmaxf(t[2], t[3]);
  float x2 = fmaxf(t[4], t[5]),   x3 = fmaxf(t[6], t[7]);
  float x4 = fmaxf(t[8], t[9]),   x5 = fmaxf(t[10], t[11]);
  float x6 = fmaxf(t[12], t[13]), x7 = fmaxf(t[14], t[15]);
  float y0 = fmaxf(x0, x1), y1 = fmaxf(x2, x3), y2 = fmaxf(x4, x5), y3 = fmaxf(x6, x7);
  float mx = fmaxf(fmaxf(y0, y1), fmaxf(y2, y3));

  // defer-max (T13): only rescale when some lane's tile-max beats m by >8 (log2 units)
  bool need = mx > m + 8.0f;
  if (__ballot(need) != 0ull) {
    float mo   = fmaxf(mx, __shfl_xor(mx, 32));
    float mnew = fmaxf(m, mo);
    float alpha = __builtin_amdgcn_exp2f(m - mnew);
    m = mnew;
    l *= alpha;
#pragma unroll
    for (int r = 0; r < 16; ++r) { o0[r] *= alpha; o1[r] *= alpha; }
  }

  float p[16];
#pragma unroll
  for (int r = 0; r < 16; ++r) p[r] = __builtin_amdgcn_exp2f(t[r] - m);
  // per-half row-sum (tree); cross-half merge deferred to epilogue
  float s0 = (p[0] + p[1]) + (p[2] + p[3]);
  float s1 = (p[4] + p[5]) + (p[6] + p[7]);
  float s2 = (p[8] + p[9]) + (p[10] + p[11]);
  float s3 = (p[12] + p[13]) + (p[14] + p[15]);
  l += (s0 + s1) + (s2 + s3);

  // P (S^T C/D regs) -> PV B-fragment (slot (hi,j) <-> kv = 16c + 8*hi + j)
  union { unsigned u[4]; bfx8 v; } P0, P1;
#pragma unroll
  for (int c = 0; c < 2; ++c) {
    unsigned a0 = pk2(p[8*c+0], p[8*c+1]);
    unsigned a1 = pk2(p[8*c+2], p[8*c+3]);
    unsigned b0 = pk2(p[8*c+4], p[8*c+5]);
    unsigned b1 = pk2(p[8*c+6], p[8*c+7]);
    unsigned xa0 = __shfl_xor(a0, 32), xa1 = __shfl_xor(a1, 32);
    unsigned xb0 = __shfl_xor(b0, 32), xb1 = __shfl_xor(b1, 32);
    unsigned* U = c ? P1.u : P0.u;
    U[0] = hi ? xb0 : a0;
    U[1] = hi ? xb1 : a1;
    U[2] = hi ? b0 : xa0;
    U[3] = hi ? b1 : xa1;
  }
  o0 = MFMA32(f.v0, P0.v, o0);
  o0 = MFMA32(f.v1, P1.v, o0);
  o1 = MFMA32(f.v2, P0.v, o1);
  o1 = MFMA32(f.v3, P1.v, o1);
}

// one 32-row q-tile, index i in [0,64): kv tiles 0..i, last one diagonal-masked
static __device__ __forceinline__ void run_qtile(
    int i, const unsigned short* __restrict__ qbb,   // qb + bh*TT*HD
    const unsigned short* __restrict__ kbase,        // kb + bh*TT*HD + l31*HD + hi*8
    const unsigned short* __restrict__ vbase,        // vtb + (bh*HD+l31)*TT + hi*8
    unsigned short* __restrict__ ybase0,             // yb + b*TT*DD + h*HD
    int l31, int hi) {
  const int q0 = i * 32;
  const float CL = 0.0450842346f;   // log2(e)/sqrt(D)
  const unsigned short* qp = qbb + (size_t)(q0 + l31) * HD + hi * 8;
  bfx8 qf[4];
#pragma unroll
  for (int dc = 0; dc < 4; ++dc) qf[dc] = scale8(ldb8(qp + dc * 16), CL);

  fx16 o0 = {}, o1 = {};
  float m = -__builtin_inff(), l = 0.f;
  const int nt = i + 1;
  const int lim = l31 - 4 * hi;

  KVfrag A, B;
  load_kv(A, kbase, vbase, 0);
  int t = 0;
  for (; t + 2 <= nt - 1; t += 2) {   // pairs of non-masked tiles, double-buffered
    load_kv(B, kbase, vbase, (t + 1) * 32);
    attn_tile<false>(A, qf, 0, hi, m, l, o0, o1);
    load_kv(A, kbase, vbase, (t + 2) * 32);
    attn_tile<false>(B, qf, 0, hi, m, l, o0, o1);
  }
  if (t == nt - 2) {                  // two left: t (non-mask, in A), t+1 (mask)
    load_kv(B, kbase, vbase, (t + 1) * 32);
    attn_tile<false>(A, qf, 0, hi, m, l, o0, o1);
    attn_tile<true>(B, qf, lim, hi, m, l, o0, o1);
  } else {                            // one left (mask), in A
    attn_tile<true>(A, qf, lim, hi, m, l, o0, o1);
  }

  l += __shfl_xor(l, 32);             // merge per-half row-sums once
  float inv = 1.0f / l;
  unsigned short* yp = ybase0 + (size_t)(q0 + l31) * DD + 4 * hi;
#pragma unroll
  for (int g = 0; g < 4; ++g) {
    ushort4 s4;
    s4.x = f2bf(o0[4*g+0] * inv); s4.y = f2bf(o0[4*g+1] * inv);
    s4.z = f2bf(o0[4*g+2] * inv); s4.w = f2bf(o0[4*g+3] * inv);
    *(ushort4*)(yp + 8 * g) = s4;
    s4.x = f2bf(o1[4*g+0] * inv); s4.y = f2bf(o1[4*g+1] * inv);
    s4.z = f2bf(o1[4*g+2] * inv); s4.w = f2bf(o1[4*g+3] * inv);
    *(ushort4*)(yp + 32 + 8 * g) = s4;
  }
}

// grid: B*H*8 blocks, 256 thr (4 waves). wave handles q-tile pair (i, 63-i):
// exactly 65 kv-tiles per wave -> perfectly balanced.
__global__ __launch_bounds__(256) void k_attn(
    const unsigned short* __restrict__ qb,   // [B,H,T,HD]
    const unsigned short* __restrict__ kb,   // [B,H,T,HD]
    const unsigned short* __restrict__ vtb,  // [B,H,HD,T]
    unsigned short* __restrict__ yb) {       // [B*T, D] bf16
  const int tid  = threadIdx.x;
  const int lane = tid & 63;
  const int w    = tid >> 6;
  const int l31  = lane & 31;
  const int hi   = lane >> 5;

  int blk = blockIdx.x;
  int j  = blk & 7;
  int h  = (blk >> 3) & 15;
  int b  = blk >> 7;
  const int i = j * 4 + w;            // 0..31
  const size_t bh = (size_t)b * HH + h;

  const unsigned short* qbb   = qb  + bh * TT * HD;
  const unsigned short* kbase = kb  + bh * TT * HD + (size_t)l31 * HD + hi * 8;
  const unsigned short* vbase = vtb + (bh * HD + l31) * TT + hi * 8;
  unsigned short* ybase0      = yb  + (size_t)b * TT * DD + h * HD;

#pragma unroll 1
  for (int pass = 0; pass < 2; ++pass) {
    int ii = pass ? (63 - i) : i;
    run_qtile(ii, qbb, kbase, vbase, ybase0, l31, hi);
  }
}

// ---------------- launch ----------------
extern "C" void kernel_launch(void* const* d_in, const int* in_sizes, int n_in,
                              void* d_out, int out_size, void* d_ws, size_t ws_size,
                              hipStream_t stream) {
  const float* x      = (const float*)d_in[0];
  const float* w_qkv  = (const float*)d_in[1];
  const float* w_proj = (const float*)d_in[2];
  float* out = (float*)d_out;

  char* ws = (char*)d_ws;
  unsigned short* xb     = (unsigned short*)(ws);
  unsigned short* wqkvT  = (unsigned short*)(ws + (size_t)(16u << 20));
  unsigned short* wprojT = (unsigned short*)(ws + (size_t)(22u << 20));
  unsigned short* qb     = (unsigned short*)(ws + (size_t)(24u << 20));
  unsigned short* kb     = (unsigned short*)(ws + (size_t)(40u << 20));
  unsigned short* vtb    = (unsigned short*)(ws + (size_t)(56u << 20));
  unsigned short* yb     = xb;   // x dead after GEMM1

  k_cast<<<4096, 256, 0, stream>>>(x, xb, BB * TT * DD);

  dim3 tb(32, 8);
  k_transpose<<<dim3(3 * DD / 32, DD / 32), tb, 0, stream>>>(w_qkv, wqkvT, DD, 3 * DD);
  k_transpose<<<dim3(DD / 32, DD / 32), tb, 0, stream>>>(w_proj, wprojT, DD, DD);

  // QKV projection: [8192,1024] x [1024,3072]
  k_gemm<1><<<dim3(3 * DD / 128, BB * TT / 128), 256, 0, stream>>>(
      xb, wqkvT, nullptr, BB * TT, 3 * DD, DD, qb, kb, vtb);

  // causal flash attention (balanced q-tile pairs)
  k_attn<<<BB * HH * 8, 256, 0, stream>>>(qb, kb, vtb, yb);

  // output projection: [8192,1024] x [1024,1024] -> f32 d_out
  k_gemm<0><<<dim3(DD / 128, BB * TT / 128), 256, 0, stream>>>(
      yb, wprojT, out, BB * TT, DD, DD, nullptr, nullptr, nullptr);
}